// Round 13
// baseline (1084.920 us; speedup 1.0000x reference)
//
#include <hip/hip_runtime.h>
#include <hip/hip_bf16.h>
#include <stdint.h>

#define TPB 256

typedef __bf16 bf16x8 __attribute__((ext_vector_type(8)));
typedef float f32x4 __attribute__((ext_vector_type(4)));
union U16x8 { uint4 u; bf16x8 b; };

typedef const uint32_t __attribute__((address_space(1))) glb_u32;
typedef uint32_t __attribute__((address_space(3))) lds_u32;

// ---------- helpers ----------
__device__ __forceinline__ float bfbits2f(uint32_t lo16) {
  union { uint32_t u; float f; } c; c.u = lo16 << 16; return c.f;
}
__device__ __forceinline__ uint16_t f2bf_rne(float f) {
  union { float f; uint32_t u; } c; c.f = f;
  uint32_t r = 0x7FFFu + ((c.u >> 16) & 1u);
  return (uint16_t)((c.u + r) >> 16);
}

// ---------- prep: W -> bf16, layout [k][chunk][cout 64][cin-within 32] ----------
// Frag load for (t,c): 16 cout rows x 32 halves contiguous -> 1KB coalesced burst.
__global__ __launch_bounds__(TPB) void prep_w_kernel(
    const float* __restrict__ W1, const float* __restrict__ W2,
    uint16_t* __restrict__ w1t, uint16_t* __restrict__ w2t)
{
  int i = blockIdx.x * TPB + threadIdx.x;
  if (i < 27 * 2048) {
    int k = i >> 11, cin = (i >> 6) & 31, cout = i & 63;
    w1t[(k * 64 + cout) * 32 + cin] = f2bf_rne(W1[i]);
  } else {
    int j = i - 27 * 2048;
    if (j < 27 * 4096) {
      int k = j >> 12, cin = (j >> 6) & 63, cout = j & 63;
      w2t[(((size_t)k * 2 + (cin >> 5)) * 64 + cout) * 32 + (cin & 31)] = f2bf_rne(W2[j]);
    }
  }
}

// ---------- prep: feats f32 [N,32] -> bf16 [(N+1),32] with zero pad row ----------
__global__ __launch_bounds__(TPB) void prep_x0_kernel(
    const float* __restrict__ feats, uint16_t* __restrict__ x0, long long N)
{
  long long t = (long long)blockIdx.x * TPB + threadIdx.x;
  if (t >= (N + 1) * 4) return;
  long long e = t * 8;
  uint4 o;
  if (e < N * 32) {
    float4 a = *(const float4*)(feats + e);
    float4 b = *(const float4*)(feats + e + 4);
    o.x = (uint32_t)f2bf_rne(a.x) | ((uint32_t)f2bf_rne(a.y) << 16);
    o.y = (uint32_t)f2bf_rne(a.z) | ((uint32_t)f2bf_rne(a.w) << 16);
    o.z = (uint32_t)f2bf_rne(b.x) | ((uint32_t)f2bf_rne(b.y) << 16);
    o.w = (uint32_t)f2bf_rne(b.z) | ((uint32_t)f2bf_rne(b.w) << 16);
  } else {
    o.x = o.y = o.z = o.w = 0;
  }
  *(uint4*)(x0 + e) = o;
}

// ---------- bucket build ----------
__global__ __launch_bounds__(TPB) void bucket_build_kernel(
    const int* __restrict__ pool_ids, int* __restrict__ count,
    int* __restrict__ members, long long N)
{
  long long i = (long long)blockIdx.x * TPB + threadIdx.x;
  if (i < N) {
    int pid = pool_ids[i];
    int slot = atomicAdd(&count[pid], 1);
    members[(long long)pid * 8 + slot] = (int)i;
  }
}

// ---------- MFMA sparse conv: BARRIER-FREE k-loop, W from global (L1/L2-hot), ----------
// W-frags + gathers double-buffered in registers; nbr indices prefetched one
// phase ahead (gA2/gB2) so no lgkm stall sits in the issue block. One
// sched_barrier(0) per phase pins {issue block} before {compute}.
template <int CIN, int R, int OCC>
__global__ __launch_bounds__(TPB, OCC) void conv_mfma_kernel(
    const uint16_t* __restrict__ x, const uint16_t* __restrict__ wt,
    const int* __restrict__ nbr, uint16_t* __restrict__ yb,
    float* __restrict__ statsrep, int N)
{
  constexpr int CHUNKS = CIN / 32;
  constexpr int ROWS = 4 * R * 16;            // 128 rows per block
  constexpr int NINTS = ROWS * 27;
  constexpr int NCH16 = NINTS / 4;

  __shared__ __align__(16) int nbrLds[NINTS]; // 13.5 KB (read-only after barrier)
  __shared__ float sred[4][128];

  const int tid = threadIdx.x;
  const int lane = tid & 63;
  const int wave = tid >> 6;
  const int l15 = lane & 15;
  const int l4 = lane >> 4;

  // XCD-chunked bijective swizzle (m204)
  int bid;
  {
    int nwg = gridDim.x, q = nwg >> 3, r = nwg & 7;
    int xcd = blockIdx.x & 7, pos = blockIdx.x >> 3;
    bid = (xcd < r ? xcd * (q + 1) : r * (q + 1) + (xcd - r) * q) + pos;
  }
  const long long row0 = (long long)bid * ROWS;

  f32x4 acc[R][4];
#pragma unroll
  for (int r = 0; r < R; ++r)
#pragma unroll
    for (int t = 0; t < 4; ++t)
      acc[r][t] = (f32x4){0.f, 0.f, 0.f, 0.f};

  // ---- stage nbr tile (coalesced DMA + scalar tail) ----
  {
    const char* nsrc = (const char*)nbr + row0 * 108;
    long long blkB = (long long)N * 108 - row0 * 108;
    int fullChunks = (int)(blkB >> 4);
    if (fullChunks > NCH16) fullChunks = NCH16;
#pragma unroll
    for (int u = 0; u < (NCH16 + TPB - 1) / TPB; ++u) {
      int idx = u * TPB + tid;
      if (idx < fullChunks)
        __builtin_amdgcn_global_load_lds((glb_u32*)(nsrc + idx * 16),
                                         (lds_u32*)((char*)nbrLds + idx * 16), 16, 0, 0);
    }
    for (int ii = fullChunks * 4 + tid; ii < NINTS; ii += TPB) {
      long long gi = row0 * 27 + ii;
      nbrLds[ii] = (gi < (long long)N * 27) ? nbr[gi] : N;
    }
  }

  auto readG = [&](int k, int (&g)[R]) {       // ds_read of nbr indices
#pragma unroll
    for (int r = 0; r < R; ++r)
      g[r] = nbrLds[((wave * R + r) * 16 + l15) * 27 + k];
  };
  auto gatherG = [&](const int (&g)[R], U16x8 (&dst)[R][CHUNKS]) {
#pragma unroll
    for (int r = 0; r < R; ++r) {
      const uint16_t* xr = x + (size_t)g[r] * CIN + (l4 << 3);
#pragma unroll
      for (int c = 0; c < CHUNKS; ++c)
        dst[r][c].u = *(const uint4*)(xr + c * 32);
    }
  };
  auto loadW = [&](int k, U16x8 (&w)[4][CHUNKS]) {
#pragma unroll
    for (int t = 0; t < 4; ++t)
#pragma unroll
      for (int c = 0; c < CHUNKS; ++c)
        w[t][c].u = *(const uint4*)(wt +
            (((size_t)k * CHUNKS + c) * 64 + t * 16 + l15) * 32 + (l4 << 3));
  };
  auto compute = [&](U16x8 (&w)[4][CHUNKS], U16x8 (&xs)[R][CHUNKS]) {
#pragma unroll
    for (int r = 0; r < R; ++r)
#pragma unroll
      for (int c = 0; c < CHUNKS; ++c)
#pragma unroll
        for (int t = 0; t < 4; ++t)
          acc[r][t] = __builtin_amdgcn_mfma_f32_16x16x32_bf16(
              xs[r][c].b, w[t][c].b, acc[r][t], 0, 0, 0);
  };

  U16x8 xA[R][CHUNKS], xB[R][CHUNKS];
  U16x8 wA[4][CHUNKS], wB[4][CHUNKS];
  int gA2[R], gB2[R], g0[R], g1[R];

  __syncthreads();                 // nbr tile landed (drains DMA + tail)
  readG(0, g0); readG(1, g1);
  gatherG(g0, xA); loadW(0, wA);
  gatherG(g1, xB); loadW(1, wB);
  readG(2, gA2); readG(3, gB2);    // prefetch indices for phases k=2,3
  __builtin_amdgcn_sched_barrier(0);

  // Phase: compute(k) | issue {gather(k+2), loadW(k+2), readG(k+4)} | fence.
  // Loads issued after compute(k) are consumed at compute(k+2): one full
  // phase (+issue) of cover; 3 waves/SIMD TLP covers the残り. No barriers.
#pragma unroll 1
  for (int kk = 0; kk < 13; ++kk) {
    compute(wA, xA);               // k = 2kk
    gatherG(gA2, xA);
    loadW(2 * kk + 2, wA);
    if (kk < 12) readG(2 * kk + 4, gA2);
    __builtin_amdgcn_sched_barrier(0);
    compute(wB, xB);               // k = 2kk+1
    if (kk < 12) {
      gatherG(gB2, xB);
      loadW(2 * kk + 3, wB);
      if (kk < 11) readG(2 * kk + 5, gB2);
      __builtin_amdgcn_sched_barrier(0);
    }
  }
  compute(wA, xA);                 // k = 26

  // ---- store y (bf16): C/D layout col=lane&15, row=(lane>>4)*4+reg ----
#pragma unroll
  for (int r = 0; r < R; ++r) {
    long long vr0 = row0 + (wave * R + r) * 16 + (l4 << 2);
#pragma unroll
    for (int reg = 0; reg < 4; ++reg) {
      long long vr = vr0 + reg;
      if (vr < N) {
        uint16_t* yr = yb + vr * 64 + l15;
#pragma unroll
        for (int t = 0; t < 4; ++t) yr[t * 16] = f2bf_rne(acc[r][t][reg]);
      }
    }
  }

  // ---- fused column stats (f32, exact from registers) ----
  float s[4], s2[4];
#pragma unroll
  for (int t = 0; t < 4; ++t) { s[t] = 0.f; s2[t] = 0.f; }
#pragma unroll
  for (int r = 0; r < R; ++r) {
    long long vr0 = row0 + (wave * R + r) * 16 + (l4 << 2);
#pragma unroll
    for (int reg = 0; reg < 4; ++reg) {
      if (vr0 + reg < N) {
#pragma unroll
        for (int t = 0; t < 4; ++t) {
          float v = acc[r][t][reg];
          s[t] += v;
          s2[t] = fmaf(v, v, s2[t]);
        }
      }
    }
  }
#pragma unroll
  for (int t = 0; t < 4; ++t) {
    s[t] += __shfl_xor(s[t], 16);
    s[t] += __shfl_xor(s[t], 32);
    s2[t] += __shfl_xor(s2[t], 16);
    s2[t] += __shfl_xor(s2[t], 32);
  }
  __syncthreads();
  if (l4 == 0) {
#pragma unroll
    for (int t = 0; t < 4; ++t) {
      sred[wave][t * 16 + l15] = s[t];
      sred[wave][64 + t * 16 + l15] = s2[t];
    }
  }
  __syncthreads();
  if (tid < 128) {
    float tot = sred[0][tid] + sred[1][tid] + sred[2][tid] + sred[3][tid];
    atomicAdd(&statsrep[(bid & 15) * 128 + tid], tot);
  }
}

// ---------- finalize ----------
__global__ void bn_finalize_kernel(const float* __restrict__ reps,
                                   float* __restrict__ fin, float n)
{
  int c = threadIdx.x;
  float s = 0.f, s2 = 0.f;
  for (int r = 0; r < 16; ++r) { s += reps[r * 128 + c]; s2 += reps[r * 128 + 64 + c]; }
  float mean = s / n;
  float var = s2 / n - mean * mean;
  fin[c] = mean;
  fin[64 + c] = rsqrtf(var + 1e-5f);
}

// ---------- BN + ReLU: yb bf16 -> x1 bf16 [(N+1),64], pad row zeros ----------
__global__ __launch_bounds__(TPB) void bn_relu_bf16_kernel(
    const uint16_t* __restrict__ yb, const float* __restrict__ fin,
    const float* __restrict__ gamma, const float* __restrict__ beta,
    uint16_t* __restrict__ x1, long long N)
{
  long long e = ((long long)blockIdx.x * TPB + threadIdx.x) * 8;
  if (e >= (N + 1) * 64) return;
  long long row = e >> 6;
  int c = (int)(e & 63);
  uint4 out;
  if (row < N) {
    uint4 v = *(const uint4*)(yb + e);
    const uint32_t vv[4] = {v.x, v.y, v.z, v.w};
    uint32_t res[4];
#pragma unroll
    for (int q = 0; q < 4; ++q) {
      int cc = c + q * 2;
      float a0 = bfbits2f(vv[q] & 0xFFFFu);
      float a1 = bfbits2f(vv[q] >> 16);
      float o0 = fmaf((a0 - fin[cc]) * fin[64 + cc], gamma[cc], beta[cc]);
      float o1 = fmaf((a1 - fin[cc + 1]) * fin[64 + cc + 1], gamma[cc + 1], beta[cc + 1]);
      o0 = o0 > 0.f ? o0 : 0.f;
      o1 = o1 > 0.f ? o1 : 0.f;
      res[q] = (uint32_t)f2bf_rne(o0) | ((uint32_t)f2bf_rne(o1) << 16);
    }
    out.x = res[0]; out.y = res[1]; out.z = res[2]; out.w = res[3];
  } else {
    out.x = out.y = out.z = out.w = 0;
  }
  *(uint4*)(x1 + e) = out;
}

// ---------- fused: BN + write xout + segment max ----------
__global__ __launch_bounds__(TPB) void pool_max_write_kernel(
    const uint16_t* __restrict__ yb, const float* __restrict__ fin,
    const float* __restrict__ gamma, const float* __restrict__ beta,
    const int* __restrict__ count, const int* __restrict__ members,
    float* __restrict__ xout, float* __restrict__ pooled, long long P)
{
  long long pid = (long long)blockIdx.x * 16 + (threadIdx.x >> 4);
  if (pid >= P) return;
  int c0 = (threadIdx.x & 15) * 4;
  float4 m = *(const float4*)(fin + c0);
  float4 r = *(const float4*)(fin + 64 + c0);
  float4 g = *(const float4*)(gamma + c0);
  float4 b = *(const float4*)(beta + c0);
  int cnt = count[pid];
  float4 acc = {-3.4e38f, -3.4e38f, -3.4e38f, -3.4e38f};
  const int* mem = members + pid * 8;
  for (int t = 0; t < cnt; ++t) {
    long long row = mem[t];
    ushort4 v = *(const ushort4*)(yb + row * 64 + c0);
    float4 o;
    o.x = fmaf((bfbits2f(v.x) - m.x) * r.x, g.x, b.x);
    o.y = fmaf((bfbits2f(v.y) - m.y) * r.y, g.y, b.y);
    o.z = fmaf((bfbits2f(v.z) - m.z) * r.z, g.z, b.z);
    o.w = fmaf((bfbits2f(v.w) - m.w) * r.w, g.w, b.w);
    *(float4*)(xout + row * 64 + c0) = o;
    acc.x = fmaxf(acc.x, o.x);
    acc.y = fmaxf(acc.y, o.y);
    acc.z = fmaxf(acc.z, o.z);
    acc.w = fmaxf(acc.w, o.w);
  }
  *(float4*)(pooled + pid * 64 + c0) = acc;
}

extern "C" void kernel_launch(void* const* d_in, const int* in_sizes, int n_in,
                              void* d_out, int out_size, void* d_ws, size_t ws_size,
                              hipStream_t stream)
{
  const float* feats  = (const float*)d_in[0];
  const float* W1     = (const float*)d_in[1];
  const float* gamma1 = (const float*)d_in[2];
  const float* beta1  = (const float*)d_in[3];
  const float* W2     = (const float*)d_in[4];
  const float* gamma2 = (const float*)d_in[5];
  const float* beta2  = (const float*)d_in[6];
  const int* nbr      = (const int*)d_in[7];
  const int* pool_ids = (const int*)d_in[8];

  const long long N = (long long)in_sizes[0] / 32;
  const long long P = (long long)out_size / 64 - N;

  // ws: [yb bf16][x0/x1 bf16][stats][fin][count P][members 8P]
  char* ws = (char*)d_ws;
  uint16_t* yb = (uint16_t*)ws;
  size_t y_bytes = ((size_t)N * 64 * 2 + 255) & ~(size_t)255;
  char* regB = ws + y_bytes;
  size_t regB_bytes = ((size_t)(N + 1) * 64 * 2 + 255) & ~(size_t)255;
  uint16_t* x0 = (uint16_t*)regB;
  uint16_t* x1 = (uint16_t*)regB;
  float* reps1 = (float*)(regB + regB_bytes);
  float* reps2 = reps1 + 16 * 128;
  float* fin1 = reps2 + 16 * 128;
  float* fin2 = fin1 + 128;
  int* count   = (int*)(fin2 + 128);
  int* members = count + P;

  float* xout = (float*)d_out;
  float* pooled = xout + (size_t)N * 64;
  uint16_t* w1t = (uint16_t*)pooled;          // temp: W tables in pooled region
  uint16_t* w2t = w1t + 27 * 2048;

  hipMemsetAsync(reps1, 0, 2 * 16 * 128 * sizeof(float), stream);
  hipMemsetAsync(count, 0, (size_t)P * 4, stream);

  prep_w_kernel<<<(27 * 2048 + 27 * 4096 + TPB - 1) / TPB, TPB, 0, stream>>>(W1, W2, w1t, w2t);
  prep_x0_kernel<<<(int)(((N + 1) * 4 + TPB - 1) / TPB), TPB, 0, stream>>>(feats, x0, N);
  bucket_build_kernel<<<(int)((N + TPB - 1) / TPB), TPB, 0, stream>>>(pool_ids, count, members, N);

  const int convBlocks = (int)((N + 127) / 128);   // R=2: 128 rows/block
  conv_mfma_kernel<32, 2, 4><<<convBlocks, TPB, 0, stream>>>(x0, w1t, nbr, yb, reps1, (int)N);
  bn_finalize_kernel<<<1, 64, 0, stream>>>(reps1, fin1, (float)N);

  long long t1 = ((N + 1) * 64) / 8;
  bn_relu_bf16_kernel<<<(int)((t1 + TPB - 1) / TPB), TPB, 0, stream>>>(
      yb, fin1, gamma1, beta1, x1, N);

  conv_mfma_kernel<64, 2, 3><<<convBlocks, TPB, 0, stream>>>(x1, w2t, nbr, yb, reps2, (int)N);
  bn_finalize_kernel<<<1, 64, 0, stream>>>(reps2, fin2, (float)N);

  pool_max_write_kernel<<<(int)((P + 15) / 16), TPB, 0, stream>>>(
      yb, fin2, gamma2, beta2, count, members, xout, pooled, P);
}

// Round 14
// 696.331 us; speedup vs baseline: 1.5581x; 1.5581x over previous
//
#include <hip/hip_runtime.h>
#include <hip/hip_bf16.h>
#include <stdint.h>

#define TPB 256

typedef __bf16 bf16x8 __attribute__((ext_vector_type(8)));
typedef float f32x4 __attribute__((ext_vector_type(4)));
union U16x8 { uint4 u; bf16x8 b; };

typedef const uint32_t __attribute__((address_space(1))) glb_u32;
typedef uint32_t __attribute__((address_space(3))) lds_u32;

// Counted wait + barrier: retire MY stage DMA (oldest), keep the NG newest
// (prefetch gathers) in flight across the barrier.
template <int N> __device__ __forceinline__ void stage_wait_barrier() {
  asm volatile("s_waitcnt vmcnt(%0)" :: "i"(N) : "memory");
  __builtin_amdgcn_s_barrier();
  __builtin_amdgcn_sched_barrier(0);
}

// ---------- helpers ----------
__device__ __forceinline__ float bfbits2f(uint32_t lo16) {
  union { uint32_t u; float f; } c; c.u = lo16 << 16; return c.f;
}
__device__ __forceinline__ uint16_t f2bf_rne(float f) {
  union { float f; uint32_t u; } c; c.f = f;
  uint32_t r = 0x7FFFu + ((c.u >> 16) & 1u);
  return (uint16_t)((c.u + r) >> 16);
}

// ---------- prep: W -> bf16, [k][cout][cin], pre-swizzled for LDS B-frag reads ----------
__global__ __launch_bounds__(TPB) void prep_w_kernel(
    const float* __restrict__ W1, const float* __restrict__ W2,
    uint16_t* __restrict__ w1t, uint16_t* __restrict__ w2t)
{
  int i = blockIdx.x * TPB + threadIdx.x;
  if (i < 27 * 2048) {
    int k = i >> 11, cin = (i >> 6) & 31, cout = i & 63;
    int cin2 = (((cin >> 3) ^ (cout & 3)) << 3) | (cin & 7);   // SWZ=3
    w1t[(k << 11) + (cout << 5) + cin2] = f2bf_rne(W1[i]);
  } else {
    int j = i - 27 * 2048;
    if (j < 27 * 4096) {
      int k = j >> 12, cin = (j >> 6) & 63, cout = j & 63;
      int cin2 = (((cin >> 3) ^ (cout & 7)) << 3) | (cin & 7); // SWZ=7
      w2t[(k << 12) + (cout << 6) + cin2] = f2bf_rne(W2[j]);
    }
  }
}

// ---------- prep: feats f32 [N,32] -> bf16 [(N+1),32] with zero pad row ----------
__global__ __launch_bounds__(TPB) void prep_x0_kernel(
    const float* __restrict__ feats, uint16_t* __restrict__ x0, long long N)
{
  long long t = (long long)blockIdx.x * TPB + threadIdx.x;
  if (t >= (N + 1) * 4) return;
  long long e = t * 8;
  uint4 o;
  if (e < N * 32) {
    float4 a = *(const float4*)(feats + e);
    float4 b = *(const float4*)(feats + e + 4);
    o.x = (uint32_t)f2bf_rne(a.x) | ((uint32_t)f2bf_rne(a.y) << 16);
    o.y = (uint32_t)f2bf_rne(a.z) | ((uint32_t)f2bf_rne(a.w) << 16);
    o.z = (uint32_t)f2bf_rne(b.x) | ((uint32_t)f2bf_rne(b.y) << 16);
    o.w = (uint32_t)f2bf_rne(b.z) | ((uint32_t)f2bf_rne(b.w) << 16);
  } else {
    o.x = o.y = o.z = o.w = 0;
  }
  *(uint4*)(x0 + e) = o;
}

// ---------- bucket build ----------
__global__ __launch_bounds__(TPB) void bucket_build_kernel(
    const int* __restrict__ pool_ids, int* __restrict__ count,
    int* __restrict__ members, long long N)
{
  long long i = (long long)blockIdx.x * TPB + threadIdx.x;
  if (i < N) {
    int pid = pool_ids[i];
    int slot = atomicAdd(&count[pid], 1);
    members[(long long)pid * 8 + slot] = (int)i;
  }
}

// ---------- MFMA sparse conv: counted-wait barriers + T5 setprio on MFMA ----------
template <int CIN, int R, int OCC>
__global__ __launch_bounds__(TPB, OCC) void conv_mfma_kernel(
    const uint16_t* __restrict__ x, const uint16_t* __restrict__ wt,
    const int* __restrict__ nbr, uint16_t* __restrict__ yb,
    float* __restrict__ statsrep, int N)
{
  constexpr int CHUNKS = CIN / 32;
  constexpr int LOGROWB = (CIN == 32) ? 6 : 7;
  constexpr int SWZ = (CIN == 32) ? 3 : 7;
  constexpr int WKB = 64 * CIN * 2;           // per-offset W bytes (4/8 KB)
  constexpr int NW = WKB / (TPB * 16);        // stage loads per thread (1/2)
  constexpr int NG = R * CHUNKS;              // gather loads per thread (2/4)
  constexpr int ROWS = 4 * R * 16;            // 128 rows per block
  constexpr int NINTS = ROWS * 27;
  constexpr int NCH16 = NINTS / 4;

  __shared__ __align__(16) char Wlds[2][WKB];
  __shared__ __align__(16) int nbrLds[NINTS]; // 13.5 KB
  __shared__ float sred[4][128];

  const int tid = threadIdx.x;
  const int lane = tid & 63;
  const int wave = tid >> 6;
  const int l15 = lane & 15;
  const int l4 = lane >> 4;

  // XCD-chunked bijective swizzle (m204)
  int bid;
  {
    int nwg = gridDim.x, q = nwg >> 3, r = nwg & 7;
    int xcd = blockIdx.x & 7, pos = blockIdx.x >> 3;
    bid = (xcd < r ? xcd * (q + 1) : r * (q + 1) + (xcd - r) * q) + pos;
  }
  const long long row0 = (long long)bid * ROWS;

  f32x4 acc[R][4];
#pragma unroll
  for (int r = 0; r < R; ++r)
#pragma unroll
    for (int t = 0; t < 4; ++t)
      acc[r][t] = (f32x4){0.f, 0.f, 0.f, 0.f};

  // ---- stage nbr tile (coalesced DMA + scalar tail) ----
  {
    const char* nsrc = (const char*)nbr + row0 * 108;
    long long blkB = (long long)N * 108 - row0 * 108;
    int fullChunks = (int)(blkB >> 4);
    if (fullChunks > NCH16) fullChunks = NCH16;
#pragma unroll
    for (int u = 0; u < (NCH16 + TPB - 1) / TPB; ++u) {
      int idx = u * TPB + tid;
      if (idx < fullChunks)
        __builtin_amdgcn_global_load_lds((glb_u32*)(nsrc + idx * 16),
                                         (lds_u32*)((char*)nbrLds + idx * 16), 16, 0, 0);
    }
    for (int ii = fullChunks * 4 + tid; ii < NINTS; ii += TPB) {
      long long gi = row0 * 27 + ii;
      nbrLds[ii] = (gi < (long long)N * 27) ? nbr[gi] : N;
    }
  }

  auto stageW = [&](int k, int b) {
    const char* src = (const char*)(wt + (size_t)k * 64 * CIN);
#pragma unroll
    for (int u = 0; u < NW; ++u) {
      int off = (tid + u * TPB) * 16;
      __builtin_amdgcn_global_load_lds((glb_u32*)(src + off),
                                       (lds_u32*)(&Wlds[b][off]), 16, 0, 0);
    }
  };
  auto gather = [&](int k, U16x8 (&dst)[R][CHUNKS]) {
#pragma unroll
    for (int r = 0; r < R; ++r) {
      int lrow = (wave * R + r) * 16 + l15;
      int g = nbrLds[lrow * 27 + k];      // invalid -> pad row N (zeros, hot line)
      const uint16_t* xr = x + (size_t)g * CIN + (l4 << 3);
#pragma unroll
      for (int c = 0; c < CHUNKS; ++c)
        dst[r][c].u = *(const uint4*)(xr + c * 32);
    }
  };
  auto compute = [&](int wsel, U16x8 (&xs)[R][CHUNKS]) {
    bf16x8 bfrag[4][CHUNKS];
#pragma unroll
    for (int t = 0; t < 4; ++t) {
      int n = t * 16 + l15;
#pragma unroll
      for (int c = 0; c < CHUNKS; ++c) {
        int colb = (l4 << 4) + (c << 6);
        int d = (n << LOGROWB) | (colb ^ ((n & SWZ) << 4));
        U16x8 tmp; tmp.u = *(const uint4*)(&Wlds[wsel][d]);
        bfrag[t][c] = tmp.b;
      }
    }
    __builtin_amdgcn_s_setprio(1);        // T5: favor MFMA-issuing wave
#pragma unroll
    for (int r = 0; r < R; ++r)
#pragma unroll
      for (int c = 0; c < CHUNKS; ++c)
#pragma unroll
        for (int t = 0; t < 4; ++t)
          acc[r][t] = __builtin_amdgcn_mfma_f32_16x16x32_bf16(
              xs[r][c].b, bfrag[t][c], acc[r][t], 0, 0, 0);
    __builtin_amdgcn_s_setprio(0);
  };

  U16x8 xA[R][CHUNKS], xB[R][CHUNKS];

  stageW(0, 0);
  __syncthreads();                 // full drain once: nbr tile + W0 landed
  gather(0, xA);

  // Phase: stage W(k+1) | fence | gather(k+1) ∥ compute(k) | vmcnt(NG)+barrier.
#pragma unroll 1
  for (int kk = 0; kk < 13; ++kk) {
    stageW(2 * kk + 1, 1);
    __builtin_amdgcn_sched_barrier(0);
    gather(2 * kk + 1, xB);
    compute(0, xA);                // k = 2kk
    stage_wait_barrier<NG>();      // W(2kk+1) landed for all; Wlds[0] free
    stageW(2 * kk + 2, 0);
    __builtin_amdgcn_sched_barrier(0);
    gather(2 * kk + 2, xA);
    compute(1, xB);                // k = 2kk+1
    stage_wait_barrier<NG>();      // W(2kk+2) landed for all; Wlds[1] free
  }
  compute(0, xA);                  // k = 26

  // ---- store y (bf16): C/D layout col=lane&15, row=(lane>>4)*4+reg ----
#pragma unroll
  for (int r = 0; r < R; ++r) {
    long long vr0 = row0 + (wave * R + r) * 16 + (l4 << 2);
#pragma unroll
    for (int reg = 0; reg < 4; ++reg) {
      long long vr = vr0 + reg;
      if (vr < N) {
        uint16_t* yr = yb + vr * 64 + l15;
#pragma unroll
        for (int t = 0; t < 4; ++t) yr[t * 16] = f2bf_rne(acc[r][t][reg]);
      }
    }
  }

  // ---- fused column stats (f32, exact from registers) ----
  float s[4], s2[4];
#pragma unroll
  for (int t = 0; t < 4; ++t) { s[t] = 0.f; s2[t] = 0.f; }
#pragma unroll
  for (int r = 0; r < R; ++r) {
    long long vr0 = row0 + (wave * R + r) * 16 + (l4 << 2);
#pragma unroll
    for (int reg = 0; reg < 4; ++reg) {
      if (vr0 + reg < N) {
#pragma unroll
        for (int t = 0; t < 4; ++t) {
          float v = acc[r][t][reg];
          s[t] += v;
          s2[t] = fmaf(v, v, s2[t]);
        }
      }
    }
  }
#pragma unroll
  for (int t = 0; t < 4; ++t) {
    s[t] += __shfl_xor(s[t], 16);
    s[t] += __shfl_xor(s[t], 32);
    s2[t] += __shfl_xor(s2[t], 16);
    s2[t] += __shfl_xor(s2[t], 32);
  }
  __syncthreads();
  if (l4 == 0) {
#pragma unroll
    for (int t = 0; t < 4; ++t) {
      sred[wave][t * 16 + l15] = s[t];
      sred[wave][64 + t * 16 + l15] = s2[t];
    }
  }
  __syncthreads();
  if (tid < 128) {
    float tot = sred[0][tid] + sred[1][tid] + sred[2][tid] + sred[3][tid];
    atomicAdd(&statsrep[(bid & 15) * 128 + tid], tot);
  }
}

// ---------- finalize ----------
__global__ void bn_finalize_kernel(const float* __restrict__ reps,
                                   float* __restrict__ fin, float n)
{
  int c = threadIdx.x;
  float s = 0.f, s2 = 0.f;
  for (int r = 0; r < 16; ++r) { s += reps[r * 128 + c]; s2 += reps[r * 128 + 64 + c]; }
  float mean = s / n;
  float var = s2 / n - mean * mean;
  fin[c] = mean;
  fin[64 + c] = rsqrtf(var + 1e-5f);
}

// ---------- BN + ReLU: yb bf16 -> x1 bf16 [(N+1),64], pad row zeros ----------
__global__ __launch_bounds__(TPB) void bn_relu_bf16_kernel(
    const uint16_t* __restrict__ yb, const float* __restrict__ fin,
    const float* __restrict__ gamma, const float* __restrict__ beta,
    uint16_t* __restrict__ x1, long long N)
{
  long long e = ((long long)blockIdx.x * TPB + threadIdx.x) * 8;
  if (e >= (N + 1) * 64) return;
  long long row = e >> 6;
  int c = (int)(e & 63);
  uint4 out;
  if (row < N) {
    uint4 v = *(const uint4*)(yb + e);
    const uint32_t vv[4] = {v.x, v.y, v.z, v.w};
    uint32_t res[4];
#pragma unroll
    for (int q = 0; q < 4; ++q) {
      int cc = c + q * 2;
      float a0 = bfbits2f(vv[q] & 0xFFFFu);
      float a1 = bfbits2f(vv[q] >> 16);
      float o0 = fmaf((a0 - fin[cc]) * fin[64 + cc], gamma[cc], beta[cc]);
      float o1 = fmaf((a1 - fin[cc + 1]) * fin[64 + cc + 1], gamma[cc + 1], beta[cc + 1]);
      o0 = o0 > 0.f ? o0 : 0.f;
      o1 = o1 > 0.f ? o1 : 0.f;
      res[q] = (uint32_t)f2bf_rne(o0) | ((uint32_t)f2bf_rne(o1) << 16);
    }
    out.x = res[0]; out.y = res[1]; out.z = res[2]; out.w = res[3];
  } else {
    out.x = out.y = out.z = out.w = 0;
  }
  *(uint4*)(x1 + e) = out;
}

// ---------- fused: BN + write xout + segment max ----------
__global__ __launch_bounds__(TPB) void pool_max_write_kernel(
    const uint16_t* __restrict__ yb, const float* __restrict__ fin,
    const float* __restrict__ gamma, const float* __restrict__ beta,
    const int* __restrict__ count, const int* __restrict__ members,
    float* __restrict__ xout, float* __restrict__ pooled, long long P)
{
  long long pid = (long long)blockIdx.x * 16 + (threadIdx.x >> 4);
  if (pid >= P) return;
  int c0 = (threadIdx.x & 15) * 4;
  float4 m = *(const float4*)(fin + c0);
  float4 r = *(const float4*)(fin + 64 + c0);
  float4 g = *(const float4*)(gamma + c0);
  float4 b = *(const float4*)(beta + c0);
  int cnt = count[pid];
  float4 acc = {-3.4e38f, -3.4e38f, -3.4e38f, -3.4e38f};
  const int* mem = members + pid * 8;
  for (int t = 0; t < cnt; ++t) {
    long long row = mem[t];
    ushort4 v = *(const ushort4*)(yb + row * 64 + c0);
    float4 o;
    o.x = fmaf((bfbits2f(v.x) - m.x) * r.x, g.x, b.x);
    o.y = fmaf((bfbits2f(v.y) - m.y) * r.y, g.y, b.y);
    o.z = fmaf((bfbits2f(v.z) - m.z) * r.z, g.z, b.z);
    o.w = fmaf((bfbits2f(v.w) - m.w) * r.w, g.w, b.w);
    *(float4*)(xout + row * 64 + c0) = o;
    acc.x = fmaxf(acc.x, o.x);
    acc.y = fmaxf(acc.y, o.y);
    acc.z = fmaxf(acc.z, o.z);
    acc.w = fmaxf(acc.w, o.w);
  }
  *(float4*)(pooled + pid * 64 + c0) = acc;
}

extern "C" void kernel_launch(void* const* d_in, const int* in_sizes, int n_in,
                              void* d_out, int out_size, void* d_ws, size_t ws_size,
                              hipStream_t stream)
{
  const float* feats  = (const float*)d_in[0];
  const float* W1     = (const float*)d_in[1];
  const float* gamma1 = (const float*)d_in[2];
  const float* beta1  = (const float*)d_in[3];
  const float* W2     = (const float*)d_in[4];
  const float* gamma2 = (const float*)d_in[5];
  const float* beta2  = (const float*)d_in[6];
  const int* nbr      = (const int*)d_in[7];
  const int* pool_ids = (const int*)d_in[8];

  const long long N = (long long)in_sizes[0] / 32;
  const long long P = (long long)out_size / 64 - N;

  // ws: [yb bf16][x0/x1 bf16][stats][fin][count P][members 8P]
  char* ws = (char*)d_ws;
  uint16_t* yb = (uint16_t*)ws;
  size_t y_bytes = ((size_t)N * 64 * 2 + 255) & ~(size_t)255;
  char* regB = ws + y_bytes;
  size_t regB_bytes = ((size_t)(N + 1) * 64 * 2 + 255) & ~(size_t)255;
  uint16_t* x0 = (uint16_t*)regB;
  uint16_t* x1 = (uint16_t*)regB;
  float* reps1 = (float*)(regB + regB_bytes);
  float* reps2 = reps1 + 16 * 128;
  float* fin1 = reps2 + 16 * 128;
  float* fin2 = fin1 + 128;
  int* count   = (int*)(fin2 + 128);
  int* members = count + P;

  float* xout = (float*)d_out;
  float* pooled = xout + (size_t)N * 64;
  uint16_t* w1t = (uint16_t*)pooled;          // temp: W tables in pooled region
  uint16_t* w2t = w1t + 27 * 2048;

  hipMemsetAsync(reps1, 0, 2 * 16 * 128 * sizeof(float), stream);
  hipMemsetAsync(count, 0, (size_t)P * 4, stream);

  prep_w_kernel<<<(27 * 2048 + 27 * 4096 + TPB - 1) / TPB, TPB, 0, stream>>>(W1, W2, w1t, w2t);
  prep_x0_kernel<<<(int)(((N + 1) * 4 + TPB - 1) / TPB), TPB, 0, stream>>>(feats, x0, N);
  bucket_build_kernel<<<(int)((N + TPB - 1) / TPB), TPB, 0, stream>>>(pool_ids, count, members, N);

  const int convBlocks = (int)((N + 127) / 128);   // R=2: 128 rows/block
  conv_mfma_kernel<32, 2, 4><<<convBlocks, TPB, 0, stream>>>(x0, w1t, nbr, yb, reps1, (int)N);
  bn_finalize_kernel<<<1, 64, 0, stream>>>(reps1, fin1, (float)N);

  long long t1 = ((N + 1) * 64) / 8;
  bn_relu_bf16_kernel<<<(int)((t1 + TPB - 1) / TPB), TPB, 0, stream>>>(
      yb, fin1, gamma1, beta1, x1, N);

  conv_mfma_kernel<64, 2, 3><<<convBlocks, TPB, 0, stream>>>(x1, w2t, nbr, yb, reps2, (int)N);
  bn_finalize_kernel<<<1, 64, 0, stream>>>(reps2, fin2, (float)N);

  pool_max_write_kernel<<<(int)((P + 15) / 16), TPB, 0, stream>>>(
      yb, fin2, gamma2, beta2, count, members, xout, pooled, P);
}

// Round 15
// 658.297 us; speedup vs baseline: 1.6481x; 1.0578x over previous
//
#include <hip/hip_runtime.h>
#include <hip/hip_bf16.h>
#include <stdint.h>

#define TPB 256

typedef __bf16 bf16x8 __attribute__((ext_vector_type(8)));
typedef float f32x4 __attribute__((ext_vector_type(4)));
union U16x8 { uint4 u; bf16x8 b; };

typedef const uint32_t __attribute__((address_space(1))) glb_u32;
typedef uint32_t __attribute__((address_space(3))) lds_u32;

// Counted wait + barrier: retire MY stage DMA (oldest), keep the NG newest
// (prefetch gathers) in flight across the barrier.
template <int N> __device__ __forceinline__ void stage_wait_barrier() {
  asm volatile("s_waitcnt vmcnt(%0)" :: "i"(N) : "memory");
  __builtin_amdgcn_s_barrier();
  __builtin_amdgcn_sched_barrier(0);
}

// ---------- helpers ----------
__device__ __forceinline__ float bfbits2f(uint32_t lo16) {
  union { uint32_t u; float f; } c; c.u = lo16 << 16; return c.f;
}
__device__ __forceinline__ uint16_t f2bf_rne(float f) {
  union { float f; uint32_t u; } c; c.f = f;
  uint32_t r = 0x7FFFu + ((c.u >> 16) & 1u);
  return (uint16_t)((c.u + r) >> 16);
}

// ---------- prep: W -> bf16, [k][cout][cin], pre-swizzled for LDS B-frag reads ----------
__global__ __launch_bounds__(TPB) void prep_w_kernel(
    const float* __restrict__ W1, const float* __restrict__ W2,
    uint16_t* __restrict__ w1t, uint16_t* __restrict__ w2t)
{
  int i = blockIdx.x * TPB + threadIdx.x;
  if (i < 27 * 2048) {
    int k = i >> 11, cin = (i >> 6) & 31, cout = i & 63;
    int cin2 = (((cin >> 3) ^ (cout & 3)) << 3) | (cin & 7);   // SWZ=3
    w1t[(k << 11) + (cout << 5) + cin2] = f2bf_rne(W1[i]);
  } else {
    int j = i - 27 * 2048;
    if (j < 27 * 4096) {
      int k = j >> 12, cin = (j >> 6) & 63, cout = j & 63;
      int cin2 = (((cin >> 3) ^ (cout & 7)) << 3) | (cin & 7); // SWZ=7
      w2t[(k << 12) + (cout << 6) + cin2] = f2bf_rne(W2[j]);
    }
  }
}

// ---------- prep: feats f32 [N,32] -> bf16 [(N+1),32] with zero pad row ----------
__global__ __launch_bounds__(TPB) void prep_x0_kernel(
    const float* __restrict__ feats, uint16_t* __restrict__ x0, long long N)
{
  long long t = (long long)blockIdx.x * TPB + threadIdx.x;
  if (t >= (N + 1) * 4) return;
  long long e = t * 8;
  uint4 o;
  if (e < N * 32) {
    float4 a = *(const float4*)(feats + e);
    float4 b = *(const float4*)(feats + e + 4);
    o.x = (uint32_t)f2bf_rne(a.x) | ((uint32_t)f2bf_rne(a.y) << 16);
    o.y = (uint32_t)f2bf_rne(a.z) | ((uint32_t)f2bf_rne(a.w) << 16);
    o.z = (uint32_t)f2bf_rne(b.x) | ((uint32_t)f2bf_rne(b.y) << 16);
    o.w = (uint32_t)f2bf_rne(b.z) | ((uint32_t)f2bf_rne(b.w) << 16);
  } else {
    o.x = o.y = o.z = o.w = 0;
  }
  *(uint4*)(x0 + e) = o;
}

// ---------- bucket build ----------
__global__ __launch_bounds__(TPB) void bucket_build_kernel(
    const int* __restrict__ pool_ids, int* __restrict__ count,
    int* __restrict__ members, long long N)
{
  long long i = (long long)blockIdx.x * TPB + threadIdx.x;
  if (i < N) {
    int pid = pool_ids[i];
    int slot = atomicAdd(&count[pid], 1);
    members[(long long)pid * 8 + slot] = (int)i;
  }
}

// ---------- MFMA sparse conv: counted-wait barriers, R=4 (fewer rounds) ----------
template <int CIN, int R, int OCC>
__global__ __launch_bounds__(TPB, OCC) void conv_mfma_kernel(
    const uint16_t* __restrict__ x, const uint16_t* __restrict__ wt,
    const int* __restrict__ nbr, uint16_t* __restrict__ yb,
    float* __restrict__ statsrep, int N)
{
  constexpr int CHUNKS = CIN / 32;
  constexpr int LOGROWB = (CIN == 32) ? 6 : 7;
  constexpr int SWZ = (CIN == 32) ? 3 : 7;
  constexpr int WKB = 64 * CIN * 2;           // per-offset W bytes (4/8 KB)
  constexpr int NW = WKB / (TPB * 16);        // stage loads per thread (1/2)
  constexpr int NG = R * CHUNKS;              // gather loads per thread (4/8)
  constexpr int ROWS = 4 * R * 16;            // 256 rows per block
  constexpr int NINTS = ROWS * 27;
  constexpr int NCH16 = NINTS / 4;

  __shared__ __align__(16) char Wlds[2][WKB];
  __shared__ __align__(16) int nbrLds[NINTS]; // 27 KB
  __shared__ float sred[4][128];

  const int tid = threadIdx.x;
  const int lane = tid & 63;
  const int wave = tid >> 6;
  const int l15 = lane & 15;
  const int l4 = lane >> 4;

  // XCD-chunked bijective swizzle (m204)
  int bid;
  {
    int nwg = gridDim.x, q = nwg >> 3, r = nwg & 7;
    int xcd = blockIdx.x & 7, pos = blockIdx.x >> 3;
    bid = (xcd < r ? xcd * (q + 1) : r * (q + 1) + (xcd - r) * q) + pos;
  }
  const long long row0 = (long long)bid * ROWS;

  f32x4 acc[R][4];
#pragma unroll
  for (int r = 0; r < R; ++r)
#pragma unroll
    for (int t = 0; t < 4; ++t)
      acc[r][t] = (f32x4){0.f, 0.f, 0.f, 0.f};

  // ---- stage nbr tile (coalesced DMA + scalar tail) ----
  {
    const char* nsrc = (const char*)nbr + row0 * 108;
    long long blkB = (long long)N * 108 - row0 * 108;
    int fullChunks = (int)(blkB >> 4);
    if (fullChunks > NCH16) fullChunks = NCH16;
#pragma unroll
    for (int u = 0; u < (NCH16 + TPB - 1) / TPB; ++u) {
      int idx = u * TPB + tid;
      if (idx < fullChunks)
        __builtin_amdgcn_global_load_lds((glb_u32*)(nsrc + idx * 16),
                                         (lds_u32*)((char*)nbrLds + idx * 16), 16, 0, 0);
    }
    for (int ii = fullChunks * 4 + tid; ii < NINTS; ii += TPB) {
      long long gi = row0 * 27 + ii;
      nbrLds[ii] = (gi < (long long)N * 27) ? nbr[gi] : N;
    }
  }

  auto stageW = [&](int k, int b) {
    const char* src = (const char*)(wt + (size_t)k * 64 * CIN);
#pragma unroll
    for (int u = 0; u < NW; ++u) {
      int off = (tid + u * TPB) * 16;
      __builtin_amdgcn_global_load_lds((glb_u32*)(src + off),
                                       (lds_u32*)(&Wlds[b][off]), 16, 0, 0);
    }
  };
  auto gather = [&](int k, U16x8 (&dst)[R][CHUNKS]) {
#pragma unroll
    for (int r = 0; r < R; ++r) {
      int lrow = (wave * R + r) * 16 + l15;
      int g = nbrLds[lrow * 27 + k];      // invalid -> pad row N (zeros, hot line)
      const uint16_t* xr = x + (size_t)g * CIN + (l4 << 3);
#pragma unroll
      for (int c = 0; c < CHUNKS; ++c)
        dst[r][c].u = *(const uint4*)(xr + c * 32);
    }
  };
  auto compute = [&](int wsel, U16x8 (&xs)[R][CHUNKS]) {
    bf16x8 bfrag[4][CHUNKS];
#pragma unroll
    for (int t = 0; t < 4; ++t) {
      int n = t * 16 + l15;
#pragma unroll
      for (int c = 0; c < CHUNKS; ++c) {
        int colb = (l4 << 4) + (c << 6);
        int d = (n << LOGROWB) | (colb ^ ((n & SWZ) << 4));
        U16x8 tmp; tmp.u = *(const uint4*)(&Wlds[wsel][d]);
        bfrag[t][c] = tmp.b;
      }
    }
#pragma unroll
    for (int r = 0; r < R; ++r)
#pragma unroll
      for (int c = 0; c < CHUNKS; ++c)
#pragma unroll
        for (int t = 0; t < 4; ++t)
          acc[r][t] = __builtin_amdgcn_mfma_f32_16x16x32_bf16(
              xs[r][c].b, bfrag[t][c], acc[r][t], 0, 0, 0);
  };

  U16x8 xA[R][CHUNKS], xB[R][CHUNKS];

  stageW(0, 0);
  __syncthreads();                 // full drain once: nbr tile + W0 landed
  gather(0, xA);

  // Phase: stage W(k+1) | fence | gather(k+1) ∥ compute(k) | vmcnt(NG)+barrier.
#pragma unroll 1
  for (int kk = 0; kk < 13; ++kk) {
    stageW(2 * kk + 1, 1);
    __builtin_amdgcn_sched_barrier(0);
    gather(2 * kk + 1, xB);
    compute(0, xA);                // k = 2kk
    stage_wait_barrier<NG>();      // W(2kk+1) landed for all; Wlds[0] free
    stageW(2 * kk + 2, 0);
    __builtin_amdgcn_sched_barrier(0);
    gather(2 * kk + 2, xA);
    compute(1, xB);                // k = 2kk+1
    stage_wait_barrier<NG>();      // W(2kk+2) landed for all; Wlds[1] free
  }
  compute(0, xA);                  // k = 26

  // ---- store y (bf16): C/D layout col=lane&15, row=(lane>>4)*4+reg ----
#pragma unroll
  for (int r = 0; r < R; ++r) {
    long long vr0 = row0 + (wave * R + r) * 16 + (l4 << 2);
#pragma unroll
    for (int reg = 0; reg < 4; ++reg) {
      long long vr = vr0 + reg;
      if (vr < N) {
        uint16_t* yr = yb + vr * 64 + l15;
#pragma unroll
        for (int t = 0; t < 4; ++t) yr[t * 16] = f2bf_rne(acc[r][t][reg]);
      }
    }
  }

  // ---- fused column stats (f32, exact from registers) ----
  float s[4], s2[4];
#pragma unroll
  for (int t = 0; t < 4; ++t) { s[t] = 0.f; s2[t] = 0.f; }
#pragma unroll
  for (int r = 0; r < R; ++r) {
    long long vr0 = row0 + (wave * R + r) * 16 + (l4 << 2);
#pragma unroll
    for (int reg = 0; reg < 4; ++reg) {
      if (vr0 + reg < N) {
#pragma unroll
        for (int t = 0; t < 4; ++t) {
          float v = acc[r][t][reg];
          s[t] += v;
          s2[t] = fmaf(v, v, s2[t]);
        }
      }
    }
  }
#pragma unroll
  for (int t = 0; t < 4; ++t) {
    s[t] += __shfl_xor(s[t], 16);
    s[t] += __shfl_xor(s[t], 32);
    s2[t] += __shfl_xor(s2[t], 16);
    s2[t] += __shfl_xor(s2[t], 32);
  }
  __syncthreads();
  if (l4 == 0) {
#pragma unroll
    for (int t = 0; t < 4; ++t) {
      sred[wave][t * 16 + l15] = s[t];
      sred[wave][64 + t * 16 + l15] = s2[t];
    }
  }
  __syncthreads();
  if (tid < 128) {
    float tot = sred[0][tid] + sred[1][tid] + sred[2][tid] + sred[3][tid];
    atomicAdd(&statsrep[(bid & 15) * 128 + tid], tot);
  }
}

// ---------- finalize ----------
__global__ void bn_finalize_kernel(const float* __restrict__ reps,
                                   float* __restrict__ fin, float n)
{
  int c = threadIdx.x;
  float s = 0.f, s2 = 0.f;
  for (int r = 0; r < 16; ++r) { s += reps[r * 128 + c]; s2 += reps[r * 128 + 64 + c]; }
  float mean = s / n;
  float var = s2 / n - mean * mean;
  fin[c] = mean;
  fin[64 + c] = rsqrtf(var + 1e-5f);
}

// ---------- BN + ReLU: yb bf16 -> x1 bf16 [(N+1),64], pad row zeros ----------
__global__ __launch_bounds__(TPB) void bn_relu_bf16_kernel(
    const uint16_t* __restrict__ yb, const float* __restrict__ fin,
    const float* __restrict__ gamma, const float* __restrict__ beta,
    uint16_t* __restrict__ x1, long long N)
{
  long long e = ((long long)blockIdx.x * TPB + threadIdx.x) * 8;
  if (e >= (N + 1) * 64) return;
  long long row = e >> 6;
  int c = (int)(e & 63);
  uint4 out;
  if (row < N) {
    uint4 v = *(const uint4*)(yb + e);
    const uint32_t vv[4] = {v.x, v.y, v.z, v.w};
    uint32_t res[4];
#pragma unroll
    for (int q = 0; q < 4; ++q) {
      int cc = c + q * 2;
      float a0 = bfbits2f(vv[q] & 0xFFFFu);
      float a1 = bfbits2f(vv[q] >> 16);
      float o0 = fmaf((a0 - fin[cc]) * fin[64 + cc], gamma[cc], beta[cc]);
      float o1 = fmaf((a1 - fin[cc + 1]) * fin[64 + cc + 1], gamma[cc + 1], beta[cc + 1]);
      o0 = o0 > 0.f ? o0 : 0.f;
      o1 = o1 > 0.f ? o1 : 0.f;
      res[q] = (uint32_t)f2bf_rne(o0) | ((uint32_t)f2bf_rne(o1) << 16);
    }
    out.x = res[0]; out.y = res[1]; out.z = res[2]; out.w = res[3];
  } else {
    out.x = out.y = out.z = out.w = 0;
  }
  *(uint4*)(x1 + e) = out;
}

// ---------- fused: BN + write xout + segment max ----------
__global__ __launch_bounds__(TPB) void pool_max_write_kernel(
    const uint16_t* __restrict__ yb, const float* __restrict__ fin,
    const float* __restrict__ gamma, const float* __restrict__ beta,
    const int* __restrict__ count, const int* __restrict__ members,
    float* __restrict__ xout, float* __restrict__ pooled, long long P)
{
  long long pid = (long long)blockIdx.x * 16 + (threadIdx.x >> 4);
  if (pid >= P) return;
  int c0 = (threadIdx.x & 15) * 4;
  float4 m = *(const float4*)(fin + c0);
  float4 r = *(const float4*)(fin + 64 + c0);
  float4 g = *(const float4*)(gamma + c0);
  float4 b = *(const float4*)(beta + c0);
  int cnt = count[pid];
  float4 acc = {-3.4e38f, -3.4e38f, -3.4e38f, -3.4e38f};
  const int* mem = members + pid * 8;
  for (int t = 0; t < cnt; ++t) {
    long long row = mem[t];
    ushort4 v = *(const ushort4*)(yb + row * 64 + c0);
    float4 o;
    o.x = fmaf((bfbits2f(v.x) - m.x) * r.x, g.x, b.x);
    o.y = fmaf((bfbits2f(v.y) - m.y) * r.y, g.y, b.y);
    o.z = fmaf((bfbits2f(v.z) - m.z) * r.z, g.z, b.z);
    o.w = fmaf((bfbits2f(v.w) - m.w) * r.w, g.w, b.w);
    *(float4*)(xout + row * 64 + c0) = o;
    acc.x = fmaxf(acc.x, o.x);
    acc.y = fmaxf(acc.y, o.y);
    acc.z = fmaxf(acc.z, o.z);
    acc.w = fmaxf(acc.w, o.w);
  }
  *(float4*)(pooled + pid * 64 + c0) = acc;
}

extern "C" void kernel_launch(void* const* d_in, const int* in_sizes, int n_in,
                              void* d_out, int out_size, void* d_ws, size_t ws_size,
                              hipStream_t stream)
{
  const float* feats  = (const float*)d_in[0];
  const float* W1     = (const float*)d_in[1];
  const float* gamma1 = (const float*)d_in[2];
  const float* beta1  = (const float*)d_in[3];
  const float* W2     = (const float*)d_in[4];
  const float* gamma2 = (const float*)d_in[5];
  const float* beta2  = (const float*)d_in[6];
  const int* nbr      = (const int*)d_in[7];
  const int* pool_ids = (const int*)d_in[8];

  const long long N = (long long)in_sizes[0] / 32;
  const long long P = (long long)out_size / 64 - N;

  // ws: [yb bf16][x0/x1 bf16][stats][fin][count P][members 8P]
  char* ws = (char*)d_ws;
  uint16_t* yb = (uint16_t*)ws;
  size_t y_bytes = ((size_t)N * 64 * 2 + 255) & ~(size_t)255;
  char* regB = ws + y_bytes;
  size_t regB_bytes = ((size_t)(N + 1) * 64 * 2 + 255) & ~(size_t)255;
  uint16_t* x0 = (uint16_t*)regB;
  uint16_t* x1 = (uint16_t*)regB;
  float* reps1 = (float*)(regB + regB_bytes);
  float* reps2 = reps1 + 16 * 128;
  float* fin1 = reps2 + 16 * 128;
  float* fin2 = fin1 + 128;
  int* count   = (int*)(fin2 + 128);
  int* members = count + P;

  float* xout = (float*)d_out;
  float* pooled = xout + (size_t)N * 64;
  uint16_t* w1t = (uint16_t*)pooled;          // temp: W tables in pooled region
  uint16_t* w2t = w1t + 27 * 2048;

  hipMemsetAsync(reps1, 0, 2 * 16 * 128 * sizeof(float), stream);
  hipMemsetAsync(count, 0, (size_t)P * 4, stream);

  prep_w_kernel<<<(27 * 2048 + 27 * 4096 + TPB - 1) / TPB, TPB, 0, stream>>>(W1, W2, w1t, w2t);
  prep_x0_kernel<<<(int)(((N + 1) * 4 + TPB - 1) / TPB), TPB, 0, stream>>>(feats, x0, N);
  bucket_build_kernel<<<(int)((N + TPB - 1) / TPB), TPB, 0, stream>>>(pool_ids, count, members, N);

  const int convBlocks = (int)((N + 255) / 256);   // R=4: 256 rows/block
  conv_mfma_kernel<32, 4, 4><<<convBlocks, TPB, 0, stream>>>(x0, w1t, nbr, yb, reps1, (int)N);
  bn_finalize_kernel<<<1, 64, 0, stream>>>(reps1, fin1, (float)N);

  long long t1 = ((N + 1) * 64) / 8;
  bn_relu_bf16_kernel<<<(int)((t1 + TPB - 1) / TPB), TPB, 0, stream>>>(
      yb, fin1, gamma1, beta1, x1, N);

  conv_mfma_kernel<64, 4, 3><<<convBlocks, TPB, 0, stream>>>(x1, w2t, nbr, yb, reps2, (int)N);
  bn_finalize_kernel<<<1, 64, 0, stream>>>(reps2, fin2, (float)N);

  pool_max_write_kernel<<<(int)((P + 15) / 16), TPB, 0, stream>>>(
      yb, fin2, gamma2, beta2, count, members, xout, pooled, P);
}